// Round 15
// baseline (85.032 us; speedup 1.0000x reference)
//
#include <hip/hip_runtime.h>
#include <hip/hip_bf16.h>

// B=4, S=4096, D=1024, H=64 single attention head.
// inputs fp32: x[4,4096,1024], Wq[1024,64], bq[64], Wk, bk, Wv, bv
// output fp32: [4,4096,64]

#define S_LEN 4096
#define D_MODEL 1024

typedef __attribute__((ext_vector_type(8))) short bf16x8;
typedef __attribute__((ext_vector_type(4))) float f32x4;
typedef __attribute__((ext_vector_type(16))) float f32x16;

__device__ inline short f2bf(float f) {
    union { float f; unsigned u; } v;
    v.f = f;
    unsigned r = v.u + 0x7fffu + ((v.u >> 16) & 1u);  // RNE
    return (short)(r >> 16);
}

__device__ inline unsigned cvt_pk(float lo, float hi) {
    unsigned r;
    asm("v_cvt_pk_bf16_f32 %0, %1, %2" : "=v"(r) : "v"(lo), "v"(hi));
    return r;
}

__device__ inline void pl32swap(unsigned& a, unsigned& b) {
    asm("v_permlane32_swap_b32 %0, %1" : "+v"(a), "+v"(b));
}

__device__ inline f32x16 fzero16() {
    f32x16 z;
#pragma unroll
    for (int i = 0; i < 16; ++i) z[i] = 0.f;
    return z;
}

// async global->LDS, 16B per lane, dest = lds_base + lane*16 (wave-uniform base)
__device__ inline void gload_lds16(const void* g, void* l) {
    __builtin_amdgcn_global_load_lds((const __attribute__((address_space(1))) void*)g,
                                     (__attribute__((address_space(3))) void*)l, 16, 0, 0);
}

// ---------------- kernel 1: W -> WtF bf16 in MFMA B-fragment order (r12, verified).
// 384 frags x 1KB. Frag f = kb*12 + ntg, kb = bk*2+kk in [0,32), ntg in [0,12).
// Frag element (lane, j): W[k][c] with k = kb*32 + (lane>>4)*8 + j,
// c = ntg*16 + (lane&15).
__global__ void prep_w(const float* __restrict__ Wq, const float* __restrict__ Wk,
                       const float* __restrict__ Wv, short* __restrict__ WtF) {
    int idx = blockIdx.x * 256 + threadIdx.x;        // [0, 196608)
    int j = idx & 7;
    int lane = (idx >> 3) & 63;
    int f = idx >> 9;                                // [0, 384)
    int ntg = f % 12;
    int kb = f / 12;                                 // [0, 32)
    int k = (kb >> 1) * 64 + (kb & 1) * 32 + (lane >> 4) * 8 + j;
    int c = ntg * 16 + (lane & 15);
    const float* W = (c < 64) ? Wq : (c < 128 ? Wk : Wv);
    WtF[idx] = f2bf(W[k * 64 + (c & 63)]);
}

// ---------------- kernel 2: QKV projection — high-TLP barrier-free frag GEMM.
// grid 1024 x 256 threads (4 independent waves). Block = 16 rows; wave w covers
// cols [w*48, w*48+48) = frag groups ntg = w*3 + {0,1,2}. Per BK=64 step:
// 6 coalesced 1KB frag loads + 4 x loads, 6 MFMA. Depth-2 frag double-buffer.
// 4 blocks/CU -> 4 waves/SIMD (vs 2 in all prior proj variants).
__launch_bounds__(256, 5)
__global__ void proj_kernel(const float* __restrict__ x, const short* __restrict__ WtF,
                            const float* __restrict__ bq, const float* __restrict__ bk,
                            const float* __restrict__ bv,
                            short* __restrict__ Qb, short* __restrict__ Kb,
                            short* __restrict__ Vt) {
    __shared__ short vsm[64][20];                    // V transpose staging (5 KB)
    const float CEXP = 0.18033688011112042f;         // log2(e)/sqrt(64)
    int w = threadIdx.x >> 6;
    int lane = threadIdx.x & 63;
    int g = lane >> 4, ln = lane & 15;
    int rowbase = blockIdx.x * 16;

    f32x4 acc[3];
#pragma unroll
    for (int i = 0; i < 3; ++i) acc[i] = (f32x4){0.f, 0.f, 0.f, 0.f};

    const float* xw = x + (size_t)(rowbase + ln) * D_MODEL + g * 8;

    auto loadF = [&](bf16x8* F, int t) {
#pragma unroll
        for (int kk = 0; kk < 2; ++kk)
#pragma unroll
            for (int j = 0; j < 3; ++j)
                F[kk * 3 + j] = *(const bf16x8*)(WtF
                    + ((((t * 2 + kk) * 12 + w * 3 + j) << 9) + lane * 8));
    };

    auto computeF = [&](const bf16x8* F, const f32x4& X0, const f32x4& X1,
                        const f32x4& X2, const f32x4& X3) {
        union { bf16x8 v; unsigned u[4]; } A;
        A.u[0] = cvt_pk(X0[0], X0[1]);
        A.u[1] = cvt_pk(X0[2], X0[3]);
        A.u[2] = cvt_pk(X1[0], X1[1]);
        A.u[3] = cvt_pk(X1[2], X1[3]);
#pragma unroll
        for (int j = 0; j < 3; ++j)
            acc[j] = __builtin_amdgcn_mfma_f32_16x16x32_bf16(A.v, F[j], acc[j], 0, 0, 0);
        A.u[0] = cvt_pk(X2[0], X2[1]);
        A.u[1] = cvt_pk(X2[2], X2[3]);
        A.u[2] = cvt_pk(X3[0], X3[1]);
        A.u[3] = cvt_pk(X3[2], X3[3]);
#pragma unroll
        for (int j = 0; j < 3; ++j)
            acc[j] = __builtin_amdgcn_mfma_f32_16x16x32_bf16(A.v, F[3 + j], acc[j], 0, 0, 0);
    };

    bf16x8 Fa[6], Fb[6];
    loadF(Fa, 0);
    f32x4 XA0 = *(const f32x4*)(xw);
    f32x4 XA1 = *(const f32x4*)(xw + 4);
    f32x4 XA2 = *(const f32x4*)(xw + 32);
    f32x4 XA3 = *(const f32x4*)(xw + 36);
    f32x4 XB0 = *(const f32x4*)(xw + 64);
    f32x4 XB1 = *(const f32x4*)(xw + 68);
    f32x4 XB2 = *(const f32x4*)(xw + 96);
    f32x4 XB3 = *(const f32x4*)(xw + 100);

#pragma unroll 1
    for (int t = 0; t < 16; t += 2) {
        loadF(Fb, t + 1 > 15 ? 15 : t + 1);
        computeF(Fa, XA0, XA1, XA2, XA3);
        {
            int nx = t + 2 > 15 ? 15 : t + 2;        // XA dead after cvts
            const float* xn = xw + nx * 64;
            XA0 = *(const f32x4*)(xn);
            XA1 = *(const f32x4*)(xn + 4);
            XA2 = *(const f32x4*)(xn + 32);
            XA3 = *(const f32x4*)(xn + 36);
        }
        loadF(Fa, t + 2 > 15 ? 15 : t + 2);
        computeF(Fb, XB0, XB1, XB2, XB3);
        {
            int nx = t + 3 > 15 ? 15 : t + 3;
            const float* xn = xw + nx * 64;
            XB0 = *(const f32x4*)(xn);
            XB1 = *(const f32x4*)(xn + 4);
            XB2 = *(const f32x4*)(xn + 32);
            XB3 = *(const f32x4*)(xn + 36);
        }
    }

    // epilogue: bias (+CEXP for Q) + writes. Wave w, frag j: cols c = (w*3+j)*16 + ln.
#pragma unroll
    for (int j = 0; j < 3; ++j) {
        int ntg = w * 3 + j;
        int c = ntg * 16 + ln;
        int proj = ntg >> 2;                         // frag col-groups align with 64-col mats
        int h = c & 63;
        float bias = (proj == 0 ? bq : (proj == 1 ? bk : bv))[h];
#pragma unroll
        for (int r = 0; r < 4; ++r) {
            int srow = rowbase + g * 4 + r;
            float v = acc[j][r] + bias;
            if (proj == 0) v *= CEXP;                // fold softmax scale into Q
            short hv = f2bf(v);
            if (proj == 0) {
                Qb[(size_t)srow * 64 + h] = hv;
            } else if (proj == 1) {
                Kb[(size_t)srow * 64 + h] = hv;
            } else {
                vsm[h][g * 4 + r] = hv;              // V: stage for coalesced transpose
            }
        }
    }
    __syncthreads();
    {   // Vt writeout: thread = (h = t>>2, c4 = t&3): uint2 of 4 s-positions
        int t = threadIdx.x;
        int h = t >> 2, c4 = t & 3;
        uint2 val = *(const uint2*)(&vsm[h][c4 * 4]);
        int bb = rowbase >> 12;
        int sg = (rowbase & 4095) + c4 * 4;
        *(uint2*)(Vt + (((size_t)(bb * 64 + h)) << 12) + sg) = val;
    }
}

// ---------------- kernel 3: flash attention — 64-key tiles, 1 barrier/iter,
// double-buffered K and V, no-max softmax. (unchanged — r10-r14 winner)
// grid 256 (4b x 64 qsuper of 64 rows) x 512 threads (8 waves = 4 sp x 2 qt).
__launch_bounds__(512)
__global__ void attn_kernel(const short* __restrict__ Qb, const short* __restrict__ Kb,
                            const short* __restrict__ Vt, float* __restrict__ out) {
    __shared__ __align__(16) char smraw[131072];     // 4 sp x (K 2x8KB | V 2x8KB)
    __shared__ float lsm[256];
    int lane = threadIdx.x & 63;
    int w = threadIdx.x >> 6;
    int l31 = lane & 31, hi = lane >> 5;
    int sp = w >> 1, qt = w & 1;

    int bid = blockIdx.x;
    int sb = (bid & 7) * 32 + (bid >> 3);            // XCD-bijective (256 % 8 == 0)
    int b = sb >> 6, qs = sb & 63;
    size_t qrow0 = ((size_t)b << 12) + (size_t)qs * 64;

    char* base = smraw + sp * 32768;
    char* kbuf = base;                               // 2 x 8KB
    char* vbuf = base + 16384;                       // 2 x 8KB

    const char* KB = (const char*)(Kb + (((size_t)b << 12) + sp * 1024) * 64);
    const char* VB = (const char*)Vt + (((size_t)b * 64) << 13) + (size_t)sp * 2048;

    auto stageT = [&](int buf, int t) {
        if (qt == 0) {
            char* dst = kbuf + buf * 8192;
#pragma unroll
            for (int i = 0; i < 8; ++i) {
                int od = i * 1024 + lane * 16;
                int row = od >> 7, colb = od & 127;
                const char* src = KB + (size_t)(t * 64 + row) * 128 + (colb ^ ((row & 7) << 4));
                gload_lds16(src, dst + i * 1024);
            }
        } else {
            char* dst = vbuf + buf * 8192;
#pragma unroll
            for (int i = 0; i < 8; ++i) {
                int od = i * 1024 + lane * 16;
                int row = od >> 7, colb = od & 127;
                const char* src = VB + (size_t)row * 8192 + t * 128 + (colb ^ ((row & 7) << 4));
                gload_lds16(src, dst + i * 1024);
            }
        }
    };

    // Q B-frags (pre-scaled in proj): col q = l31, k-dim d
    bf16x8 qf[4];
    {
        const short* qp = Qb + (qrow0 + qt * 32 + l31) * 64 + hi * 8;
#pragma unroll
        for (int ks = 0; ks < 4; ++ks) qf[ks] = *(const bf16x8*)(qp + ks * 16);
    }

    f32x16 oacc0 = fzero16(), oacc1 = fzero16();     // O^T[h][q]
    float lacc[16];
#pragma unroll
    for (int r = 0; r < 16; ++r) lacc[r] = 0.f;

    int swz = (l31 & 7) << 4;
    stageT(0, 0);

#pragma unroll 1
    for (int t = 0; t < 16; ++t) {
        asm volatile("s_waitcnt vmcnt(0)" ::: "memory");
        __builtin_amdgcn_s_barrier();
        __builtin_amdgcn_sched_barrier(0);
        if (t < 15) stageT((t + 1) & 1, t + 1);      // other buffer: overwrite-safe

        const char* kc = kbuf + (t & 1) * 8192;
        const char* vc = vbuf + (t & 1) * 8192;

        // ---- K frags + QK^T (S^T: row = key, col = q = l31)
        bf16x8 kf[8];
#pragma unroll
        for (int kt = 0; kt < 2; ++kt)
#pragma unroll
            for (int ks = 0; ks < 4; ++ks)
                kf[kt * 4 + ks] = *(const bf16x8*)(kc + (kt * 32 + l31) * 128
                                                  + ((ks * 32 + hi * 16) ^ swz));
        f32x16 s0 = fzero16(), s1 = fzero16();
#pragma unroll
        for (int ks = 0; ks < 4; ++ks) {
            s0 = __builtin_amdgcn_mfma_f32_32x32x16_bf16(kf[ks], qf[ks], s0, 0, 0, 0);
            s1 = __builtin_amdgcn_mfma_f32_32x32x16_bf16(kf[4 + ks], qf[ks], s1, 0, 0, 0);
        }

        // ---- V frags (A-operand: row = h, k = key)
        bf16x8 vf[8];
#pragma unroll
        for (int ht = 0; ht < 2; ++ht)
#pragma unroll
            for (int kk = 0; kk < 4; ++kk)
                vf[ht * 4 + kk] = *(const bf16x8*)(vc + (ht * 32 + l31) * 128
                                                   + ((kk * 32 + hi * 16) ^ swz));

        // ---- no-max softmax: p = exp2(s); per-lane l accumulation
        float p0[16], p1[16];
#pragma unroll
        for (int r = 0; r < 16; ++r) p0[r] = exp2f(s0[r]);
#pragma unroll
        for (int r = 0; r < 16; ++r) p1[r] = exp2f(s1[r]);
#pragma unroll
        for (int r = 0; r < 16; ++r) lacc[r] += p0[r] + p1[r];

        // ---- pack P -> 4 bf16 B-frag tuples (keys 0-15,16-31,32-47,48-63)
        union { unsigned u[4]; bf16x8 v; } t00, t01, t10, t11;
        {
            unsigned D[8];
#pragma unroll
            for (int dw = 0; dw < 8; ++dw) D[dw] = cvt_pk(p0[2 * dw], p0[2 * dw + 1]);
            pl32swap(D[0], D[2]); pl32swap(D[1], D[3]);
            pl32swap(D[4], D[6]); pl32swap(D[5], D[7]);
            t00.u[0] = D[0]; t00.u[1] = D[1]; t00.u[2] = D[2]; t00.u[3] = D[3];
            t01.u[0] = D[4]; t01.u[1] = D[5]; t01.u[2] = D[6]; t01.u[3] = D[7];
        }
        {
            unsigned D[8];
#pragma unroll
            for (int dw = 0; dw < 8; ++dw) D[dw] = cvt_pk(p1[2 * dw], p1[2 * dw + 1]);
            pl32swap(D[0], D[2]); pl32swap(D[1], D[3]);
            pl32swap(D[4], D[6]); pl32swap(D[5], D[7]);
            t10.u[0] = D[0]; t10.u[1] = D[1]; t10.u[2] = D[2]; t10.u[3] = D[3];
            t11.u[0] = D[4]; t11.u[1] = D[5]; t11.u[2] = D[6]; t11.u[3] = D[7];
        }

        // ---- O += P V
        oacc0 = __builtin_amdgcn_mfma_f32_32x32x16_bf16(vf[0], t00.v, oacc0, 0, 0, 0);
        oacc1 = __builtin_amdgcn_mfma_f32_32x32x16_bf16(vf[4], t00.v, oacc1, 0, 0, 0);
        oacc0 = __builtin_amdgcn_mfma_f32_32x32x16_bf16(vf[1], t01.v, oacc0, 0, 0, 0);
        oacc1 = __builtin_amdgcn_mfma_f32_32x32x16_bf16(vf[5], t01.v, oacc1, 0, 0, 0);
        oacc0 = __builtin_amdgcn_mfma_f32_32x32x16_bf16(vf[2], t10.v, oacc0, 0, 0, 0);
        oacc1 = __builtin_amdgcn_mfma_f32_32x32x16_bf16(vf[6], t10.v, oacc1, 0, 0, 0);
        oacc0 = __builtin_amdgcn_mfma_f32_32x32x16_bf16(vf[3], t11.v, oacc0, 0, 0, 0);
        oacc1 = __builtin_amdgcn_mfma_f32_32x32x16_bf16(vf[7], t11.v, oacc1, 0, 0, 0);
    }

    // ---- final l per lane (q = l31): tree + one swap-half shuffle
    float lfin;
    {
        float lt[8];
#pragma unroll
        for (int r = 0; r < 8; ++r) lt[r] = lacc[r] + lacc[r + 8];
#pragma unroll
        for (int st = 4; st >= 1; st >>= 1)
#pragma unroll
            for (int r = 0; r < 4; ++r)
                if (r < st) lt[r] += lt[r + st];
        lfin = lt[0] + __shfl_xor(lt[0], 32);
    }

    // ---- merge partials across sp (pure sums)
    __syncthreads();                                 // all compute done; alias staging LDS
    float* osm = (float*)smraw;                      // [8 w][32 q][68]
    {
        float* ow = osm + (size_t)(w * 32 + l31) * 68;
#pragma unroll
        for (int r = 0; r < 16; ++r) {
            int h = (r & 3) + 8 * (r >> 2) + 4 * hi;
            ow[h] = oacc0[r];
            ow[32 + h] = oacc1[r];
        }
        if (hi == 0) lsm[w * 32 + l31] = lfin;
    }
    __syncthreads();
    {
        int tq = threadIdx.x >> 3, hb = (threadIdx.x & 7) * 8;
        int qt2 = tq >> 5, ql = tq & 31;
        f32x4 oa = (f32x4){0.f, 0.f, 0.f, 0.f}, ob = (f32x4){0.f, 0.f, 0.f, 0.f};
        float lsum = 0.f;
#pragma unroll
        for (int sp2 = 0; sp2 < 4; ++sp2) {
            int w2 = sp2 * 2 + qt2;
            lsum += lsm[w2 * 32 + ql];
            const float* src = osm + (size_t)(w2 * 32 + ql) * 68 + hb;
            f32x4 x0 = *(const f32x4*)src;
            f32x4 x1 = *(const f32x4*)(src + 4);
#pragma unroll
            for (int j = 0; j < 4; ++j) { oa[j] += x0[j]; ob[j] += x1[j]; }
        }
        float inv = 1.f / lsum;
        f32x4 r0, r1;
#pragma unroll
        for (int j = 0; j < 4; ++j) { r0[j] = oa[j] * inv; r1[j] = ob[j] * inv; }
        float* op = out + (qrow0 + tq) * 64 + hb;
        *(f32x4*)op = r0;
        *(f32x4*)(op + 4) = r1;
    }
}

extern "C" void kernel_launch(void* const* d_in, const int* in_sizes, int n_in,
                              void* d_out, int out_size, void* d_ws, size_t ws_size,
                              hipStream_t stream) {
    const float* x  = (const float*)d_in[0];
    const float* Wq = (const float*)d_in[1];
    const float* bq = (const float*)d_in[2];
    const float* Wk = (const float*)d_in[3];
    const float* bk = (const float*)d_in[4];
    const float* Wv = (const float*)d_in[5];
    const float* bv = (const float*)d_in[6];

    short* ws = (short*)d_ws;
    short* WtF = ws;                      // 384 frags x 512 shorts = 192*1024
    short* Qb = WtF + 192 * 1024;         // 16384*64 (pre-scaled by log2(e)/8)
    short* Kb = Qb + 16384 * 64;
    short* Vt = Kb + 16384 * 64;          // [4][64][4096] transposed

    prep_w<<<768, 256, 0, stream>>>(Wq, Wk, Wv, WtF);
    proj_kernel<<<1024, 256, 0, stream>>>(x, WtF, bq, bk, bv, Qb, Kb, Vt);
    attn_kernel<<<256, 512, 0, stream>>>(Qb, Kb, Vt, (float*)d_out);
}

// Round 16
// 60.085 us; speedup vs baseline: 1.4152x; 1.4152x over previous
//
#include <hip/hip_runtime.h>
#include <hip/hip_bf16.h>

// B=4, S=4096, D=1024, H=64 single attention head.
// inputs fp32: x[4,4096,1024], Wq[1024,64], bq[64], Wk, bk, Wv, bv
// output fp32: [4,4096,64]

#define S_LEN 4096
#define D_MODEL 1024

typedef __attribute__((ext_vector_type(8))) short bf16x8;
typedef __attribute__((ext_vector_type(4))) float f32x4;
typedef __attribute__((ext_vector_type(16))) float f32x16;

__device__ inline short f2bf(float f) {
    union { float f; unsigned u; } v;
    v.f = f;
    unsigned r = v.u + 0x7fffu + ((v.u >> 16) & 1u);  // RNE
    return (short)(r >> 16);
}

__device__ inline unsigned cvt_pk(float lo, float hi) {
    unsigned r;
    asm("v_cvt_pk_bf16_f32 %0, %1, %2" : "=v"(r) : "v"(lo), "v"(hi));
    return r;
}

__device__ inline void pl32swap(unsigned& a, unsigned& b) {
    asm("v_permlane32_swap_b32 %0, %1" : "+v"(a), "+v"(b));
}

__device__ inline f32x16 fzero16() {
    f32x16 z;
#pragma unroll
    for (int i = 0; i < 16; ++i) z[i] = 0.f;
    return z;
}

// async global->LDS, 16B per lane, dest = lds_base + lane*16 (wave-uniform base)
__device__ inline void gload_lds16(const void* g, void* l) {
    __builtin_amdgcn_global_load_lds((const __attribute__((address_space(1))) void*)g,
                                     (__attribute__((address_space(3))) void*)l, 16, 0, 0);
}

// ---------------- kernel 1: W -> WtF bf16 in MFMA B-fragment order (r12, verified).
// 384 frags x 1KB. Frag f = kb*12 + ntg, kb in [0,32), ntg in [0,12).
// Element (lane, j): W[k][c], k = (kb>>1)*64 + (kb&1)*32 + (lane>>4)*8 + j,
// c = ntg*16 + (lane&15). Step bk's 24 frags are the contiguous 24 KB at bk*24576.
__global__ void prep_w(const float* __restrict__ Wq, const float* __restrict__ Wk,
                       const float* __restrict__ Wv, short* __restrict__ WtF) {
    int idx = blockIdx.x * 256 + threadIdx.x;        // [0, 196608)
    int j = idx & 7;
    int lane = (idx >> 3) & 63;
    int f = idx >> 9;                                // [0, 384)
    int ntg = f % 12;
    int kb = f / 12;                                 // [0, 32)
    int k = (kb >> 1) * 64 + (kb & 1) * 32 + (lane >> 4) * 8 + j;
    int c = ntg * 16 + (lane & 15);
    const float* W = (c < 64) ? Wq : (c < 128 ? Wk : Wv);
    WtF[idx] = f2bf(W[k * 64 + (c & 63)]);
}

// ---------------- kernel 2: QKV projection — x staged to LDS linearly (NEW).
// grid 256 x 512 threads (8 waves). Block = 64 rows x 192 cols, 16 BK=64 steps.
// Per step: stage x-tile [64 rows][256B] (16 KB, full-line linear gloads, XOR
// within-row pre-swizzle) + W frag-tile (24 KB linear). attn's proven schedule:
// vmcnt(0) -> s_barrier -> sched_barrier -> stage(next) -> compute(cur).
__launch_bounds__(512)
__global__ void proj_kernel(const float* __restrict__ x, const short* __restrict__ WtF,
                            const float* __restrict__ bq, const float* __restrict__ bk,
                            const float* __restrict__ bv,
                            short* __restrict__ Qb, short* __restrict__ Kb,
                            short* __restrict__ Vt) {
    __shared__ __align__(16) char smem[81920];       // x dbuf 2x16KB @0 | W dbuf 2x24KB @32768
    const float CEXP = 0.18033688011112042f;         // log2(e)/sqrt(64)
    int w = threadIdx.x >> 6;
    int lane = threadIdx.x & 63;
    int g = lane >> 4, ln = lane & 15;
    int rt = w >> 1, nh = w & 1;
    int rowbase = blockIdx.x * 64;

    char* xbuf = smem;                               // 2 x 16384
    char* wbuf = smem + 32768;                       // 2 x 24576
    const char* xB = (const char*)x;
    const char* WtB = (const char*)WtF;

    // stage x-tile for step bk: rows rowbase..+63, bytes [bk*256, +256) of each row.
    // Linear dest; source = full-line contiguous per row, XOR-permuted within row.
    auto stageX = [&](int buf, int bkt) {
#pragma unroll
        for (int i = 0; i < 2; ++i) {
            int od = w * 2048 + i * 1024 + lane * 16;
            int row = od >> 8, col = od & 255;
            const char* src = xB + (size_t)(rowbase + row) * 4096 + bkt * 256
                              + (col ^ ((row & 7) << 5));
            gload_lds16(src, xbuf + buf * 16384 + w * 2048 + i * 1024);
        }
    };
    // stage W frag-tile for step bk: contiguous 24 KB, pure linear copy.
    auto stageW = [&](int buf, int bkt) {
#pragma unroll
        for (int i = 0; i < 3; ++i) {
            const char* src = WtB + (size_t)bkt * 24576 + w * 3072 + i * 1024 + lane * 16;
            gload_lds16(src, wbuf + buf * 24576 + w * 3072 + i * 1024);
        }
    };

    f32x4 acc[6];
#pragma unroll
    for (int i = 0; i < 6; ++i) acc[i] = (f32x4){0.f, 0.f, 0.f, 0.f};

    stageX(0, 0);
    stageW(0, 0);

    int arow = rt * 16 + ln;                         // this lane's A-frag row
    int aswz = (arow & 7) << 5;

#pragma unroll 1
    for (int t = 0; t < 16; ++t) {
        asm volatile("s_waitcnt vmcnt(0)" ::: "memory");
        __builtin_amdgcn_s_barrier();
        __builtin_amdgcn_sched_barrier(0);
        if (t < 15) {
            stageX((t + 1) & 1, t + 1);
            stageW((t + 1) & 1, t + 1);
        }
        const char* xc = xbuf + (t & 1) * 16384;
        const char* wc = wbuf + (t & 1) * 24576;

#pragma unroll
        for (int kk = 0; kk < 2; ++kk) {
            // A-frag: x[arow][kk*32 + g*8 .. +7] from LDS (swizzled)
            int cb = (kk * 128 + g * 32) ^ aswz;
            f32x4 X0 = *(const f32x4*)(xc + arow * 256 + cb);
            f32x4 X1 = *(const f32x4*)(xc + arow * 256 + cb + 16);
            union { bf16x8 v; unsigned u[4]; } A;
            A.u[0] = cvt_pk(X0[0], X0[1]);
            A.u[1] = cvt_pk(X0[2], X0[3]);
            A.u[2] = cvt_pk(X1[0], X1[1]);
            A.u[3] = cvt_pk(X1[2], X1[3]);
#pragma unroll
            for (int nt = 0; nt < 6; ++nt) {
                int fr = kk * 12 + nh * 6 + nt;      // frag index within step tile
                bf16x8 bfr = *(const bf16x8*)(wc + fr * 1024 + lane * 16);
                acc[nt] = __builtin_amdgcn_mfma_f32_16x16x32_bf16(A.v, bfr, acc[nt], 0, 0, 0);
            }
        }
    }

    // epilogue: bias (+CEXP for Q) + writes. Global col c = (nh*6+nt)*16 + ln.
    __syncthreads();                                 // staging done; alias smem as vsm
    short* vsm = (short*)smem;                       // [64][72]
#pragma unroll
    for (int nt = 0; nt < 6; ++nt) {
        int ntg = nh * 6 + nt;
        int c = ntg * 16 + ln;
        int proj = ntg >> 2;
        int h = c & 63;
        float bias = (proj == 0 ? bq : (proj == 1 ? bk : bv))[h];
#pragma unroll
        for (int r = 0; r < 4; ++r) {
            int srow = rowbase + rt * 16 + g * 4 + r;
            float v = acc[nt][r] + bias;
            if (proj == 0) v *= CEXP;                // fold softmax scale into Q
            short hv = f2bf(v);
            if (proj == 0) {
                Qb[(size_t)srow * 64 + h] = hv;
            } else if (proj == 1) {
                Kb[(size_t)srow * 64 + h] = hv;
            } else {
                vsm[h * 72 + rt * 16 + g * 4 + r] = hv;  // V: stage for transpose
            }
        }
    }
    __syncthreads();
    {   // coalesced Vt writeout: thread = (h = t>>3, c = t&7): 16B of 8 rows
        int t = threadIdx.x;
        int h = t >> 3, c = t & 7;
        bf16x8 val = *(const bf16x8*)&vsm[h * 72 + c * 8];
        int bb = rowbase >> 12;
        int sg = (rowbase & 4095) + c * 8;
        *(bf16x8*)(Vt + ((size_t)(bb * 64 + h) << 12) + sg) = val;
    }
}

// ---------------- kernel 3: flash attention — 64-key tiles, 1 barrier/iter,
// double-buffered K and V, no-max softmax. (unchanged — r10-r15 winner, ~22 us)
// grid 256 (4b x 64 qsuper of 64 rows) x 512 threads (8 waves = 4 sp x 2 qt).
__launch_bounds__(512)
__global__ void attn_kernel(const short* __restrict__ Qb, const short* __restrict__ Kb,
                            const short* __restrict__ Vt, float* __restrict__ out) {
    __shared__ __align__(16) char smraw[131072];     // 4 sp x (K 2x8KB | V 2x8KB)
    __shared__ float lsm[256];
    int lane = threadIdx.x & 63;
    int w = threadIdx.x >> 6;
    int l31 = lane & 31, hi = lane >> 5;
    int sp = w >> 1, qt = w & 1;

    int bid = blockIdx.x;
    int sb = (bid & 7) * 32 + (bid >> 3);            // XCD-bijective (256 % 8 == 0)
    int b = sb >> 6, qs = sb & 63;
    size_t qrow0 = ((size_t)b << 12) + (size_t)qs * 64;

    char* base = smraw + sp * 32768;
    char* kbuf = base;                               // 2 x 8KB
    char* vbuf = base + 16384;                       // 2 x 8KB

    const char* KB = (const char*)(Kb + (((size_t)b << 12) + sp * 1024) * 64);
    const char* VB = (const char*)Vt + (((size_t)b * 64) << 13) + (size_t)sp * 2048;

    auto stageT = [&](int buf, int t) {
        if (qt == 0) {
            char* dst = kbuf + buf * 8192;
#pragma unroll
            for (int i = 0; i < 8; ++i) {
                int od = i * 1024 + lane * 16;
                int row = od >> 7, colb = od & 127;
                const char* src = KB + (size_t)(t * 64 + row) * 128 + (colb ^ ((row & 7) << 4));
                gload_lds16(src, dst + i * 1024);
            }
        } else {
            char* dst = vbuf + buf * 8192;
#pragma unroll
            for (int i = 0; i < 8; ++i) {
                int od = i * 1024 + lane * 16;
                int row = od >> 7, colb = od & 127;
                const char* src = VB + (size_t)row * 8192 + t * 128 + (colb ^ ((row & 7) << 4));
                gload_lds16(src, dst + i * 1024);
            }
        }
    };

    // Q B-frags (pre-scaled in proj): col q = l31, k-dim d
    bf16x8 qf[4];
    {
        const short* qp = Qb + (qrow0 + qt * 32 + l31) * 64 + hi * 8;
#pragma unroll
        for (int ks = 0; ks < 4; ++ks) qf[ks] = *(const bf16x8*)(qp + ks * 16);
    }

    f32x16 oacc0 = fzero16(), oacc1 = fzero16();     // O^T[h][q]
    float lacc[16];
#pragma unroll
    for (int r = 0; r < 16; ++r) lacc[r] = 0.f;

    int swz = (l31 & 7) << 4;
    stageT(0, 0);

#pragma unroll 1
    for (int t = 0; t < 16; ++t) {
        asm volatile("s_waitcnt vmcnt(0)" ::: "memory");
        __builtin_amdgcn_s_barrier();
        __builtin_amdgcn_sched_barrier(0);
        if (t < 15) stageT((t + 1) & 1, t + 1);      // other buffer: overwrite-safe

        const char* kc = kbuf + (t & 1) * 8192;
        const char* vc = vbuf + (t & 1) * 8192;

        // ---- K frags + QK^T (S^T: row = key, col = q = l31)
        bf16x8 kf[8];
#pragma unroll
        for (int kt = 0; kt < 2; ++kt)
#pragma unroll
            for (int ks = 0; ks < 4; ++ks)
                kf[kt * 4 + ks] = *(const bf16x8*)(kc + (kt * 32 + l31) * 128
                                                  + ((ks * 32 + hi * 16) ^ swz));
        f32x16 s0 = fzero16(), s1 = fzero16();
#pragma unroll
        for (int ks = 0; ks < 4; ++ks) {
            s0 = __builtin_amdgcn_mfma_f32_32x32x16_bf16(kf[ks], qf[ks], s0, 0, 0, 0);
            s1 = __builtin_amdgcn_mfma_f32_32x32x16_bf16(kf[4 + ks], qf[ks], s1, 0, 0, 0);
        }

        // ---- V frags (A-operand: row = h, k = key)
        bf16x8 vf[8];
#pragma unroll
        for (int ht = 0; ht < 2; ++ht)
#pragma unroll
            for (int kk = 0; kk < 4; ++kk)
                vf[ht * 4 + kk] = *(const bf16x8*)(vc + (ht * 32 + l31) * 128
                                                   + ((kk * 32 + hi * 16) ^ swz));

        // ---- no-max softmax: p = exp2(s); per-lane l accumulation
        float p0[16], p1[16];
#pragma unroll
        for (int r = 0; r < 16; ++r) p0[r] = exp2f(s0[r]);
#pragma unroll
        for (int r = 0; r < 16; ++r) p1[r] = exp2f(s1[r]);
#pragma unroll
        for (int r = 0; r < 16; ++r) lacc[r] += p0[r] + p1[r];

        // ---- pack P -> 4 bf16 B-frag tuples (keys 0-15,16-31,32-47,48-63)
        union { unsigned u[4]; bf16x8 v; } t00, t01, t10, t11;
        {
            unsigned D[8];
#pragma unroll
            for (int dw = 0; dw < 8; ++dw) D[dw] = cvt_pk(p0[2 * dw], p0[2 * dw + 1]);
            pl32swap(D[0], D[2]); pl32swap(D[1], D[3]);
            pl32swap(D[4], D[6]); pl32swap(D[5], D[7]);
            t00.u[0] = D[0]; t00.u[1] = D[1]; t00.u[2] = D[2]; t00.u[3] = D[3];
            t01.u[0] = D[4]; t01.u[1] = D[5]; t01.u[2] = D[6]; t01.u[3] = D[7];
        }
        {
            unsigned D[8];
#pragma unroll
            for (int dw = 0; dw < 8; ++dw) D[dw] = cvt_pk(p1[2 * dw], p1[2 * dw + 1]);
            pl32swap(D[0], D[2]); pl32swap(D[1], D[3]);
            pl32swap(D[4], D[6]); pl32swap(D[5], D[7]);
            t10.u[0] = D[0]; t10.u[1] = D[1]; t10.u[2] = D[2]; t10.u[3] = D[3];
            t11.u[0] = D[4]; t11.u[1] = D[5]; t11.u[2] = D[6]; t11.u[3] = D[7];
        }

        // ---- O += P V
        oacc0 = __builtin_amdgcn_mfma_f32_32x32x16_bf16(vf[0], t00.v, oacc0, 0, 0, 0);
        oacc1 = __builtin_amdgcn_mfma_f32_32x32x16_bf16(vf[4], t00.v, oacc1, 0, 0, 0);
        oacc0 = __builtin_amdgcn_mfma_f32_32x32x16_bf16(vf[1], t01.v, oacc0, 0, 0, 0);
        oacc1 = __builtin_amdgcn_mfma_f32_32x32x16_bf16(vf[5], t01.v, oacc1, 0, 0, 0);
        oacc0 = __builtin_amdgcn_mfma_f32_32x32x16_bf16(vf[2], t10.v, oacc0, 0, 0, 0);
        oacc1 = __builtin_amdgcn_mfma_f32_32x32x16_bf16(vf[6], t10.v, oacc1, 0, 0, 0);
        oacc0 = __builtin_amdgcn_mfma_f32_32x32x16_bf16(vf[3], t11.v, oacc0, 0, 0, 0);
        oacc1 = __builtin_amdgcn_mfma_f32_32x32x16_bf16(vf[7], t11.v, oacc1, 0, 0, 0);
    }

    // ---- final l per lane (q = l31): tree + one swap-half shuffle
    float lfin;
    {
        float lt[8];
#pragma unroll
        for (int r = 0; r < 8; ++r) lt[r] = lacc[r] + lacc[r + 8];
#pragma unroll
        for (int st = 4; st >= 1; st >>= 1)
#pragma unroll
            for (int r = 0; r < 4; ++r)
                if (r < st) lt[r] += lt[r + st];
        lfin = lt[0] + __shfl_xor(lt[0], 32);
    }

    // ---- merge partials across sp (pure sums)
    __syncthreads();                                 // all compute done; alias staging LDS
    float* osm = (float*)smraw;                      // [8 w][32 q][68]
    {
        float* ow = osm + (size_t)(w * 32 + l31) * 68;
#pragma unroll
        for (int r = 0; r < 16; ++r) {
            int h = (r & 3) + 8 * (r >> 2) + 4 * hi;
            ow[h] = oacc0[r];
            ow[32 + h] = oacc1[r];
        }
        if (hi == 0) lsm[w * 32 + l31] = lfin;
    }
    __syncthreads();
    {
        int tq = threadIdx.x >> 3, hb = (threadIdx.x & 7) * 8;
        int qt2 = tq >> 5, ql = tq & 31;
        f32x4 oa = (f32x4){0.f, 0.f, 0.f, 0.f}, ob = (f32x4){0.f, 0.f, 0.f, 0.f};
        float lsum = 0.f;
#pragma unroll
        for (int sp2 = 0; sp2 < 4; ++sp2) {
            int w2 = sp2 * 2 + qt2;
            lsum += lsm[w2 * 32 + ql];
            const float* src = osm + (size_t)(w2 * 32 + ql) * 68 + hb;
            f32x4 x0 = *(const f32x4*)src;
            f32x4 x1 = *(const f32x4*)(src + 4);
#pragma unroll
            for (int j = 0; j < 4; ++j) { oa[j] += x0[j]; ob[j] += x1[j]; }
        }
        float inv = 1.f / lsum;
        f32x4 r0, r1;
#pragma unroll
        for (int j = 0; j < 4; ++j) { r0[j] = oa[j] * inv; r1[j] = ob[j] * inv; }
        float* op = out + (qrow0 + tq) * 64 + hb;
        *(f32x4*)op = r0;
        *(f32x4*)(op + 4) = r1;
    }
}

extern "C" void kernel_launch(void* const* d_in, const int* in_sizes, int n_in,
                              void* d_out, int out_size, void* d_ws, size_t ws_size,
                              hipStream_t stream) {
    const float* x  = (const float*)d_in[0];
    const float* Wq = (const float*)d_in[1];
    const float* bq = (const float*)d_in[2];
    const float* Wk = (const float*)d_in[3];
    const float* bk = (const float*)d_in[4];
    const float* Wv = (const float*)d_in[5];
    const float* bv = (const float*)d_in[6];

    short* ws = (short*)d_ws;
    short* WtF = ws;                      // 384 frags x 512 shorts = 192*1024
    short* Qb = WtF + 192 * 1024;         // 16384*64 (pre-scaled by log2(e)/8)
    short* Kb = Qb + 16384 * 64;
    short* Vt = Kb + 16384 * 64;          // [4][64][4096] transposed

    prep_w<<<768, 256, 0, stream>>>(Wq, Wk, Wv, WtF);
    proj_kernel<<<256, 512, 0, stream>>>(x, WtF, bq, bk, bv, Qb, Kb, Vt);
    attn_kernel<<<256, 512, 0, stream>>>(Qb, Kb, Vt, (float*)d_out);
}

// Round 17
// 58.899 us; speedup vs baseline: 1.4437x; 1.0201x over previous
//
#include <hip/hip_runtime.h>
#include <hip/hip_bf16.h>

// B=4, S=4096, D=1024, H=64 single attention head.
// inputs fp32: x[4,4096,1024], Wq[1024,64], bq[64], Wk, bk, Wv, bv
// output fp32: [4,4096,64]

#define S_LEN 4096
#define D_MODEL 1024

typedef __attribute__((ext_vector_type(8))) short bf16x8;
typedef __attribute__((ext_vector_type(4))) float f32x4;
typedef __attribute__((ext_vector_type(16))) float f32x16;

__device__ inline short f2bf(float f) {
    union { float f; unsigned u; } v;
    v.f = f;
    unsigned r = v.u + 0x7fffu + ((v.u >> 16) & 1u);  // RNE
    return (short)(r >> 16);
}

__device__ inline unsigned cvt_pk(float lo, float hi) {
    unsigned r;
    asm("v_cvt_pk_bf16_f32 %0, %1, %2" : "=v"(r) : "v"(lo), "v"(hi));
    return r;
}

__device__ inline void pl32swap(unsigned& a, unsigned& b) {
    asm("v_permlane32_swap_b32 %0, %1" : "+v"(a), "+v"(b));
}

__device__ inline f32x16 fzero16() {
    f32x16 z;
#pragma unroll
    for (int i = 0; i < 16; ++i) z[i] = 0.f;
    return z;
}

// async global->LDS, 16B per lane, dest = lds_base + lane*16 (wave-uniform base)
__device__ inline void gload_lds16(const void* g, void* l) {
    __builtin_amdgcn_global_load_lds((const __attribute__((address_space(1))) void*)g,
                                     (__attribute__((address_space(3))) void*)l, 16, 0, 0);
}

// ---------------- kernel 1: W -> WtF bf16 in MFMA B-fragment order (verified).
// 384 frags x 1KB. Frag f = kb*12 + ntg, kb in [0,32), ntg in [0,12).
// Element (lane, j): W[k][c], k = (kb>>1)*64 + (kb&1)*32 + (lane>>4)*8 + j,
// c = ntg*16 + (lane&15). Step bk's 24 frags are the contiguous 24 KB at bk*24576.
__global__ void prep_w(const float* __restrict__ Wq, const float* __restrict__ Wk,
                       const float* __restrict__ Wv, short* __restrict__ WtF) {
    int idx = blockIdx.x * 256 + threadIdx.x;        // [0, 196608)
    int j = idx & 7;
    int lane = (idx >> 3) & 63;
    int f = idx >> 9;                                // [0, 384)
    int ntg = f % 12;
    int kb = f / 12;                                 // [0, 32)
    int k = (kb >> 1) * 64 + (kb & 1) * 32 + (lane >> 4) * 8 + j;
    int c = ntg * 16 + (lane & 15);
    const float* W = (c < 64) ? Wq : (c < 128 ? Wk : Wv);
    WtF[idx] = f2bf(W[k * 64 + (c & 63)]);
}

// ---------------- kernel 2: QKV projection — LDS-staged x (r16) + depth-2
// counted-vmcnt pipeline (NEW). grid 256 x 512 threads (8 waves). Block = 64 rows
// x 192 cols, 16 BK=64 steps. Triple-buffered X (3x16KB) and W (3x24KB) rings;
// per iter: vmcnt(5) [tile t done, tile t+1's 5 loads/wave stay in flight] ->
// s_barrier -> stage tile t+2 -> compute tile t.
__launch_bounds__(512)
__global__ void proj_kernel(const float* __restrict__ x, const short* __restrict__ WtF,
                            const float* __restrict__ bq, const float* __restrict__ bk,
                            const float* __restrict__ bv,
                            short* __restrict__ Qb, short* __restrict__ Kb,
                            short* __restrict__ Vt) {
    __shared__ __align__(16) char smem[122880];      // X ring 3x16KB @0 | W ring 3x24KB @49152
    const float CEXP = 0.18033688011112042f;         // log2(e)/sqrt(64)
    int w = threadIdx.x >> 6;
    int lane = threadIdx.x & 63;
    int g = lane >> 4, ln = lane & 15;
    int rt = w >> 1, nh = w & 1;
    int rowbase = blockIdx.x * 64;

    char* xbuf = smem;                               // 3 x 16384
    char* wbuf = smem + 49152;                       // 3 x 24576
    const char* xB = (const char*)x;
    const char* WtB = (const char*)WtF;

    // stage x-tile for step bk: rows rowbase..+63, bytes [bk*256, +256) of each row.
    // Linear dest; source full-line contiguous per row, XOR-permuted within row.
    // 2 gload instrs per wave.
    auto stageX = [&](int buf, int bkt) {
#pragma unroll
        for (int i = 0; i < 2; ++i) {
            int od = w * 2048 + i * 1024 + lane * 16;
            int row = od >> 8, col = od & 255;
            const char* src = xB + (size_t)(rowbase + row) * 4096 + bkt * 256
                              + (col ^ ((row & 7) << 5));
            gload_lds16(src, xbuf + buf * 16384 + w * 2048 + i * 1024);
        }
    };
    // stage W frag-tile for step bk: contiguous 24 KB, linear. 3 gloads per wave.
    auto stageW = [&](int buf, int bkt) {
#pragma unroll
        for (int i = 0; i < 3; ++i) {
            const char* src = WtB + (size_t)bkt * 24576 + w * 3072 + i * 1024 + lane * 16;
            gload_lds16(src, wbuf + buf * 24576 + w * 3072 + i * 1024);
        }
    };

    f32x4 acc[6];
#pragma unroll
    for (int i = 0; i < 6; ++i) acc[i] = (f32x4){0.f, 0.f, 0.f, 0.f};

    // prologue: stage tiles 0 and 1 (per wave: X2+W3 each, FIFO [X0,W0,X1,W1])
    stageX(0, 0);
    stageW(0, 0);
    stageX(1, 1);
    stageW(1, 1);

    int arow = rt * 16 + ln;                         // this lane's A-frag row
    int aswz = (arow & 7) << 5;

    int jc = 0;                                      // ring slot of tile t
#pragma unroll 1
    for (int t = 0; t < 16; ++t) {
        // wait tile t (drain its 5/wave); tile t+1's 5/wave stay in flight
        asm volatile("s_waitcnt vmcnt(5)" ::: "memory");
        __builtin_amdgcn_s_barrier();
        __builtin_amdgcn_sched_barrier(0);
        {
            int js = jc + 2; if (js >= 3) js -= 3;
            int tn = t + 2 > 15 ? 15 : t + 2;        // redundant tail keeps counts uniform
            stageX(js, tn);
            stageW(js, tn);
        }
        const char* xc = xbuf + jc * 16384;
        const char* wc = wbuf + jc * 24576;

#pragma unroll
        for (int kk = 0; kk < 2; ++kk) {
            // A-frag: x[arow][kk*32 + g*8 .. +7] from LDS (swizzled)
            int cb = (kk * 128 + g * 32) ^ aswz;
            f32x4 X0 = *(const f32x4*)(xc + arow * 256 + cb);
            f32x4 X1 = *(const f32x4*)(xc + arow * 256 + cb + 16);
            union { bf16x8 v; unsigned u[4]; } A;
            A.u[0] = cvt_pk(X0[0], X0[1]);
            A.u[1] = cvt_pk(X0[2], X0[3]);
            A.u[2] = cvt_pk(X1[0], X1[1]);
            A.u[3] = cvt_pk(X1[2], X1[3]);
#pragma unroll
            for (int nt = 0; nt < 6; ++nt) {
                int fr = kk * 12 + nh * 6 + nt;      // frag index within step tile
                bf16x8 bfr = *(const bf16x8*)(wc + fr * 1024 + lane * 16);
                acc[nt] = __builtin_amdgcn_mfma_f32_16x16x32_bf16(A.v, bfr, acc[nt], 0, 0, 0);
            }
        }
        jc = jc + 1; if (jc >= 3) jc = 0;
    }

    // epilogue: bias (+CEXP for Q) + writes. Global col c = (nh*6+nt)*16 + ln.
    __syncthreads();                                 // drains DMA; alias smem as vsm
    short* vsm = (short*)smem;                       // [64][72]
#pragma unroll
    for (int nt = 0; nt < 6; ++nt) {
        int ntg = nh * 6 + nt;
        int c = ntg * 16 + ln;
        int proj = ntg >> 2;
        int h = c & 63;
        float bias = (proj == 0 ? bq : (proj == 1 ? bk : bv))[h];
#pragma unroll
        for (int r = 0; r < 4; ++r) {
            int srow = rowbase + rt * 16 + g * 4 + r;
            float v = acc[nt][r] + bias;
            if (proj == 0) v *= CEXP;                // fold softmax scale into Q
            short hv = f2bf(v);
            if (proj == 0) {
                Qb[(size_t)srow * 64 + h] = hv;
            } else if (proj == 1) {
                Kb[(size_t)srow * 64 + h] = hv;
            } else {
                vsm[h * 72 + rt * 16 + g * 4 + r] = hv;  // V: stage for transpose
            }
        }
    }
    __syncthreads();
    {   // coalesced Vt writeout: thread = (h = t>>3, c = t&7): 16B of 8 rows
        int t = threadIdx.x;
        int h = t >> 3, c = t & 7;
        bf16x8 val = *(const bf16x8*)&vsm[h * 72 + c * 8];
        int bb = rowbase >> 12;
        int sg = (rowbase & 4095) + c * 8;
        *(bf16x8*)(Vt + ((size_t)(bb * 64 + h) << 12) + sg) = val;
    }
}

// ---------------- kernel 3: flash attention — 64-key tiles, 1 barrier/iter,
// double-buffered K and V, no-max softmax. (unchanged — r10-r16 winner, ~22 us)
// grid 256 (4b x 64 qsuper of 64 rows) x 512 threads (8 waves = 4 sp x 2 qt).
__launch_bounds__(512)
__global__ void attn_kernel(const short* __restrict__ Qb, const short* __restrict__ Kb,
                            const short* __restrict__ Vt, float* __restrict__ out) {
    __shared__ __align__(16) char smraw[131072];     // 4 sp x (K 2x8KB | V 2x8KB)
    __shared__ float lsm[256];
    int lane = threadIdx.x & 63;
    int w = threadIdx.x >> 6;
    int l31 = lane & 31, hi = lane >> 5;
    int sp = w >> 1, qt = w & 1;

    int bid = blockIdx.x;
    int sb = (bid & 7) * 32 + (bid >> 3);            // XCD-bijective (256 % 8 == 0)
    int b = sb >> 6, qs = sb & 63;
    size_t qrow0 = ((size_t)b << 12) + (size_t)qs * 64;

    char* base = smraw + sp * 32768;
    char* kbuf = base;                               // 2 x 8KB
    char* vbuf = base + 16384;                       // 2 x 8KB

    const char* KB = (const char*)(Kb + (((size_t)b << 12) + sp * 1024) * 64);
    const char* VB = (const char*)Vt + (((size_t)b * 64) << 13) + (size_t)sp * 2048;

    auto stageT = [&](int buf, int t) {
        if (qt == 0) {
            char* dst = kbuf + buf * 8192;
#pragma unroll
            for (int i = 0; i < 8; ++i) {
                int od = i * 1024 + lane * 16;
                int row = od >> 7, colb = od & 127;
                const char* src = KB + (size_t)(t * 64 + row) * 128 + (colb ^ ((row & 7) << 4));
                gload_lds16(src, dst + i * 1024);
            }
        } else {
            char* dst = vbuf + buf * 8192;
#pragma unroll
            for (int i = 0; i < 8; ++i) {
                int od = i * 1024 + lane * 16;
                int row = od >> 7, colb = od & 127;
                const char* src = VB + (size_t)row * 8192 + t * 128 + (colb ^ ((row & 7) << 4));
                gload_lds16(src, dst + i * 1024);
            }
        }
    };

    // Q B-frags (pre-scaled in proj): col q = l31, k-dim d
    bf16x8 qf[4];
    {
        const short* qp = Qb + (qrow0 + qt * 32 + l31) * 64 + hi * 8;
#pragma unroll
        for (int ks = 0; ks < 4; ++ks) qf[ks] = *(const bf16x8*)(qp + ks * 16);
    }

    f32x16 oacc0 = fzero16(), oacc1 = fzero16();     // O^T[h][q]
    float lacc[16];
#pragma unroll
    for (int r = 0; r < 16; ++r) lacc[r] = 0.f;

    int swz = (l31 & 7) << 4;
    stageT(0, 0);

#pragma unroll 1
    for (int t = 0; t < 16; ++t) {
        asm volatile("s_waitcnt vmcnt(0)" ::: "memory");
        __builtin_amdgcn_s_barrier();
        __builtin_amdgcn_sched_barrier(0);
        if (t < 15) stageT((t + 1) & 1, t + 1);      // other buffer: overwrite-safe

        const char* kc = kbuf + (t & 1) * 8192;
        const char* vc = vbuf + (t & 1) * 8192;

        // ---- K frags + QK^T (S^T: row = key, col = q = l31)
        bf16x8 kf[8];
#pragma unroll
        for (int kt = 0; kt < 2; ++kt)
#pragma unroll
            for (int ks = 0; ks < 4; ++ks)
                kf[kt * 4 + ks] = *(const bf16x8*)(kc + (kt * 32 + l31) * 128
                                                  + ((ks * 32 + hi * 16) ^ swz));
        f32x16 s0 = fzero16(), s1 = fzero16();
#pragma unroll
        for (int ks = 0; ks < 4; ++ks) {
            s0 = __builtin_amdgcn_mfma_f32_32x32x16_bf16(kf[ks], qf[ks], s0, 0, 0, 0);
            s1 = __builtin_amdgcn_mfma_f32_32x32x16_bf16(kf[4 + ks], qf[ks], s1, 0, 0, 0);
        }

        // ---- V frags (A-operand: row = h, k = key)
        bf16x8 vf[8];
#pragma unroll
        for (int ht = 0; ht < 2; ++ht)
#pragma unroll
            for (int kk = 0; kk < 4; ++kk)
                vf[ht * 4 + kk] = *(const bf16x8*)(vc + (ht * 32 + l31) * 128
                                                   + ((kk * 32 + hi * 16) ^ swz));

        // ---- no-max softmax: p = exp2(s); per-lane l accumulation
        float p0[16], p1[16];
#pragma unroll
        for (int r = 0; r < 16; ++r) p0[r] = exp2f(s0[r]);
#pragma unroll
        for (int r = 0; r < 16; ++r) p1[r] = exp2f(s1[r]);
#pragma unroll
        for (int r = 0; r < 16; ++r) lacc[r] += p0[r] + p1[r];

        // ---- pack P -> 4 bf16 B-frag tuples (keys 0-15,16-31,32-47,48-63)
        union { unsigned u[4]; bf16x8 v; } t00, t01, t10, t11;
        {
            unsigned D[8];
#pragma unroll
            for (int dw = 0; dw < 8; ++dw) D[dw] = cvt_pk(p0[2 * dw], p0[2 * dw + 1]);
            pl32swap(D[0], D[2]); pl32swap(D[1], D[3]);
            pl32swap(D[4], D[6]); pl32swap(D[5], D[7]);
            t00.u[0] = D[0]; t00.u[1] = D[1]; t00.u[2] = D[2]; t00.u[3] = D[3];
            t01.u[0] = D[4]; t01.u[1] = D[5]; t01.u[2] = D[6]; t01.u[3] = D[7];
        }
        {
            unsigned D[8];
#pragma unroll
            for (int dw = 0; dw < 8; ++dw) D[dw] = cvt_pk(p1[2 * dw], p1[2 * dw + 1]);
            pl32swap(D[0], D[2]); pl32swap(D[1], D[3]);
            pl32swap(D[4], D[6]); pl32swap(D[5], D[7]);
            t10.u[0] = D[0]; t10.u[1] = D[1]; t10.u[2] = D[2]; t10.u[3] = D[3];
            t11.u[0] = D[4]; t11.u[1] = D[5]; t11.u[2] = D[6]; t11.u[3] = D[7];
        }

        // ---- O += P V
        oacc0 = __builtin_amdgcn_mfma_f32_32x32x16_bf16(vf[0], t00.v, oacc0, 0, 0, 0);
        oacc1 = __builtin_amdgcn_mfma_f32_32x32x16_bf16(vf[4], t00.v, oacc1, 0, 0, 0);
        oacc0 = __builtin_amdgcn_mfma_f32_32x32x16_bf16(vf[1], t01.v, oacc0, 0, 0, 0);
        oacc1 = __builtin_amdgcn_mfma_f32_32x32x16_bf16(vf[5], t01.v, oacc1, 0, 0, 0);
        oacc0 = __builtin_amdgcn_mfma_f32_32x32x16_bf16(vf[2], t10.v, oacc0, 0, 0, 0);
        oacc1 = __builtin_amdgcn_mfma_f32_32x32x16_bf16(vf[6], t10.v, oacc1, 0, 0, 0);
        oacc0 = __builtin_amdgcn_mfma_f32_32x32x16_bf16(vf[3], t11.v, oacc0, 0, 0, 0);
        oacc1 = __builtin_amdgcn_mfma_f32_32x32x16_bf16(vf[7], t11.v, oacc1, 0, 0, 0);
    }

    // ---- final l per lane (q = l31): tree + one swap-half shuffle
    float lfin;
    {
        float lt[8];
#pragma unroll
        for (int r = 0; r < 8; ++r) lt[r] = lacc[r] + lacc[r + 8];
#pragma unroll
        for (int st = 4; st >= 1; st >>= 1)
#pragma unroll
            for (int r = 0; r < 4; ++r)
                if (r < st) lt[r] += lt[r + st];
        lfin = lt[0] + __shfl_xor(lt[0], 32);
    }

    // ---- merge partials across sp (pure sums)
    __syncthreads();                                 // all compute done; alias staging LDS
    float* osm = (float*)smraw;                      // [8 w][32 q][68]
    {
        float* ow = osm + (size_t)(w * 32 + l31) * 68;
#pragma unroll
        for (int r = 0; r < 16; ++r) {
            int h = (r & 3) + 8 * (r >> 2) + 4 * hi;
            ow[h] = oacc0[r];
            ow[32 + h] = oacc1[r];
        }
        if (hi == 0) lsm[w * 32 + l31] = lfin;
    }
    __syncthreads();
    {
        int tq = threadIdx.x >> 3, hb = (threadIdx.x & 7) * 8;
        int qt2 = tq >> 5, ql = tq & 31;
        f32x4 oa = (f32x4){0.f, 0.f, 0.f, 0.f}, ob = (f32x4){0.f, 0.f, 0.f, 0.f};
        float lsum = 0.f;
#pragma unroll
        for (int sp2 = 0; sp2 < 4; ++sp2) {
            int w2 = sp2 * 2 + qt2;
            lsum += lsm[w2 * 32 + ql];
            const float* src = osm + (size_t)(w2 * 32 + ql) * 68 + hb;
            f32x4 x0 = *(const f32x4*)src;
            f32x4 x1 = *(const f32x4*)(src + 4);
#pragma unroll
            for (int j = 0; j < 4; ++j) { oa[j] += x0[j]; ob[j] += x1[j]; }
        }
        float inv = 1.f / lsum;
        f32x4 r0, r1;
#pragma unroll
        for (int j = 0; j < 4; ++j) { r0[j] = oa[j] * inv; r1[j] = ob[j] * inv; }
        float* op = out + (qrow0 + tq) * 64 + hb;
        *(f32x4*)op = r0;
        *(f32x4*)(op + 4) = r1;
    }
}

extern "C" void kernel_launch(void* const* d_in, const int* in_sizes, int n_in,
                              void* d_out, int out_size, void* d_ws, size_t ws_size,
                              hipStream_t stream) {
    const float* x  = (const float*)d_in[0];
    const float* Wq = (const float*)d_in[1];
    const float* bq = (const float*)d_in[2];
    const float* Wk = (const float*)d_in[3];
    const float* bk = (const float*)d_in[4];
    const float* Wv = (const float*)d_in[5];
    const float* bv = (const float*)d_in[6];

    short* ws = (short*)d_ws;
    short* WtF = ws;                      // 384 frags x 512 shorts = 192*1024
    short* Qb = WtF + 192 * 1024;         // 16384*64 (pre-scaled by log2(e)/8)
    short* Kb = Qb + 16384 * 64;
    short* Vt = Kb + 16384 * 64;          // [4][64][4096] transposed

    prep_w<<<768, 256, 0, stream>>>(Wq, Wk, Wv, WtF);
    proj_kernel<<<256, 512, 0, stream>>>(x, WtF, bq, bk, bv, Qb, Kb, Vt);
    attn_kernel<<<256, 512, 0, stream>>>(Qb, Kb, Vt, (float*)d_out);
}